// Round 1
// baseline (8636.935 us; speedup 1.0000x reference)
//
#include <hip/hip_runtime.h>
#include <math.h>

#define E_DIM   1024
#define M_ROWS  4096   // B*T = 32*128
#define NKP     320    // N*k = 64*5
#define K_STEPS 8
#define GATES_N 4096   // 4*E

__device__ __forceinline__ float sigmoidf_(float v) { return 1.0f / (1.0f + expf(-v)); }

// ---------------------------------------------------------------------------
// Gx[M x 4096] = A[M x 1024] @ B[4096 x 1024]^T + b_ih[col] + b_hh[col]
// 64x64 tile, BK=16, 256 threads, 4x4 micro-tile per thread.
// ---------------------------------------------------------------------------
__global__ __launch_bounds__(256) void gemm_bias_kernel(
    const float* __restrict__ A, const float* __restrict__ B,
    const float* __restrict__ b_ih, const float* __restrict__ b_hh,
    float* __restrict__ out)
{
    __shared__ float As[64][17];
    __shared__ float Bs[64][17];
    const int row0 = blockIdx.y * 64, col0 = blockIdx.x * 64;
    const int tid = threadIdx.x;
    const int tx = tid & 15, ty = tid >> 4;
    const int lrow = tid >> 2, lc4 = (tid & 3) * 4;
    float acc[4][4] = {};
    for (int k0 = 0; k0 < E_DIM; k0 += 16) {
        float4 a4 = *reinterpret_cast<const float4*>(&A[(size_t)(row0 + lrow) * E_DIM + k0 + lc4]);
        float4 b4 = *reinterpret_cast<const float4*>(&B[(size_t)(col0 + lrow) * E_DIM + k0 + lc4]);
        As[lrow][lc4 + 0] = a4.x; As[lrow][lc4 + 1] = a4.y; As[lrow][lc4 + 2] = a4.z; As[lrow][lc4 + 3] = a4.w;
        Bs[lrow][lc4 + 0] = b4.x; Bs[lrow][lc4 + 1] = b4.y; Bs[lrow][lc4 + 2] = b4.z; Bs[lrow][lc4 + 3] = b4.w;
        __syncthreads();
        #pragma unroll
        for (int kk = 0; kk < 16; ++kk) {
            float a[4], b[4];
            #pragma unroll
            for (int i = 0; i < 4; ++i) a[i] = As[ty * 4 + i][kk];
            #pragma unroll
            for (int j = 0; j < 4; ++j) b[j] = Bs[tx * 4 + j][kk];
            #pragma unroll
            for (int i = 0; i < 4; ++i)
                #pragma unroll
                for (int j = 0; j < 4; ++j) acc[i][j] += a[i] * b[j];
        }
        __syncthreads();
    }
    #pragma unroll
    for (int i = 0; i < 4; ++i) {
        int r = row0 + ty * 4 + i;
        #pragma unroll
        for (int j = 0; j < 4; ++j) {
            int ccol = col0 + tx * 4 + j;
            out[(size_t)r * GATES_N + ccol] = acc[i][j] + b_ih[ccol] + b_hh[ccol];
        }
    }
}

// ---------------------------------------------------------------------------
// Fused per-step LSTM: gates = Gx + h_in @ W_hh^T, then cell update.
// Block computes 64 rows x 64 e-cols for ALL 4 gates; epilogue applies
// sigmoid/tanh, c update, skip connection. h,c updated in place.
// grid = (E/64=16, M/64=64)
// ---------------------------------------------------------------------------
__global__ __launch_bounds__(256) void lstm_step_kernel(
    const float* __restrict__ h_in, const float* __restrict__ Whh,
    const float* __restrict__ Gx, const float* __restrict__ x,
    float* __restrict__ h, float* __restrict__ c)
{
    __shared__ float As[64][17];
    __shared__ float Bs[4][64][17];
    const int e0 = blockIdx.x * 64, row0 = blockIdx.y * 64;
    const int tid = threadIdx.x;
    const int tx = tid & 15, ty = tid >> 4;
    const int lrow = tid >> 2, lc4 = (tid & 3) * 4;
    float acc[4][4][4] = {};  // [gate][i][j]
    for (int k0 = 0; k0 < E_DIM; k0 += 16) {
        float4 a4 = *reinterpret_cast<const float4*>(&h_in[(size_t)(row0 + lrow) * E_DIM + k0 + lc4]);
        As[lrow][lc4 + 0] = a4.x; As[lrow][lc4 + 1] = a4.y; As[lrow][lc4 + 2] = a4.z; As[lrow][lc4 + 3] = a4.w;
        #pragma unroll
        for (int g = 0; g < 4; ++g) {
            float4 b4 = *reinterpret_cast<const float4*>(
                &Whh[(size_t)(g * E_DIM + e0 + lrow) * E_DIM + k0 + lc4]);
            Bs[g][lrow][lc4 + 0] = b4.x; Bs[g][lrow][lc4 + 1] = b4.y;
            Bs[g][lrow][lc4 + 2] = b4.z; Bs[g][lrow][lc4 + 3] = b4.w;
        }
        __syncthreads();
        #pragma unroll
        for (int kk = 0; kk < 16; ++kk) {
            float a[4];
            #pragma unroll
            for (int i = 0; i < 4; ++i) a[i] = As[ty * 4 + i][kk];
            #pragma unroll
            for (int g = 0; g < 4; ++g) {
                float b[4];
                #pragma unroll
                for (int j = 0; j < 4; ++j) b[j] = Bs[g][tx * 4 + j][kk];
                #pragma unroll
                for (int i = 0; i < 4; ++i)
                    #pragma unroll
                    for (int j = 0; j < 4; ++j) acc[g][i][j] += a[i] * b[j];
            }
        }
        __syncthreads();
    }
    #pragma unroll
    for (int i = 0; i < 4; ++i) {
        int r = row0 + ty * 4 + i;
        #pragma unroll
        for (int j = 0; j < 4; ++j) {
            int e = e0 + tx * 4 + j;
            size_t gbase = (size_t)r * GATES_N + e;
            float gi = acc[0][i][j] + Gx[gbase];
            float gf = acc[1][i][j] + Gx[gbase + E_DIM];
            float gg = acc[2][i][j] + Gx[gbase + 2 * E_DIM];
            float go = acc[3][i][j] + Gx[gbase + 3 * E_DIM];
            float i_ = sigmoidf_(gi), f_ = sigmoidf_(gf), o_ = sigmoidf_(go);
            float g_ = tanhf(gg);
            size_t he = (size_t)r * E_DIM + e;
            float cn = f_ * c[he] + i_ * g_;
            c[he] = cn;
            h[he] = o_ * tanhf(cn) + x[he];
        }
    }
}

// ---------------------------------------------------------------------------
// Attention: one block per (b,t). dots over 320 supports, softmax, weighted sum.
// ---------------------------------------------------------------------------
__global__ __launch_bounds__(256) void attn_kernel(
    const float* __restrict__ h_in, const float* __restrict__ sup,
    float* __restrict__ r)
{
    const int bt = blockIdx.x;
    const int b = bt >> 7;  // T = 128
    const float* S = sup + (size_t)b * NKP * E_DIM;
    __shared__ float qs[E_DIM];
    __shared__ float dots[NKP];
    __shared__ float red[8];
    const int tid = threadIdx.x;
    const int w = tid >> 6, lane = tid & 63;

    // load q
    {
        float4 q4 = *reinterpret_cast<const float4*>(&h_in[(size_t)bt * E_DIM + tid * 4]);
        qs[tid * 4 + 0] = q4.x; qs[tid * 4 + 1] = q4.y; qs[tid * 4 + 2] = q4.z; qs[tid * 4 + 3] = q4.w;
    }
    __syncthreads();

    // dots[j] = q . S[j]
    for (int j = w; j < NKP; j += 4) {
        const float* Sj = S + (size_t)j * E_DIM;
        float p = 0.f;
        #pragma unroll
        for (int m = 0; m < 16; ++m) p += qs[lane + 64 * m] * Sj[lane + 64 * m];
        #pragma unroll
        for (int off = 32; off > 0; off >>= 1) p += __shfl_down(p, off);
        if (lane == 0) dots[j] = p;
    }
    __syncthreads();

    // softmax over 320
    float m = -3.4e38f;
    for (int j = tid; j < NKP; j += 256) m = fmaxf(m, dots[j]);
    #pragma unroll
    for (int off = 32; off > 0; off >>= 1) m = fmaxf(m, __shfl_down(m, off));
    if (lane == 0) red[w] = m;
    __syncthreads();
    if (tid == 0) red[4] = fmaxf(fmaxf(red[0], red[1]), fmaxf(red[2], red[3]));
    __syncthreads();
    float gmax = red[4];
    float s = 0.f;
    for (int j = tid; j < NKP; j += 256) { float ev = expf(dots[j] - gmax); dots[j] = ev; s += ev; }
    #pragma unroll
    for (int off = 32; off > 0; off >>= 1) s += __shfl_down(s, off);
    if (lane == 0) red[w] = s;
    __syncthreads();
    if (tid == 0) red[5] = red[0] + red[1] + red[2] + red[3];
    __syncthreads();
    float inv = 1.0f / red[5];

    // r = sum_j att[j] * S[j]
    float4 acc = make_float4(0.f, 0.f, 0.f, 0.f);
    const int e = tid * 4;
    for (int j = 0; j < NKP; ++j) {
        float a = dots[j];
        float4 s4 = *reinterpret_cast<const float4*>(&S[(size_t)j * E_DIM + e]);
        acc.x += a * s4.x; acc.y += a * s4.y; acc.z += a * s4.z; acc.w += a * s4.w;
    }
    acc.x *= inv; acc.y *= inv; acc.z *= inv; acc.w *= inv;
    *reinterpret_cast<float4*>(&r[(size_t)bt * E_DIM + e]) = acc;
}

// h_in = h + r
__global__ __launch_bounds__(256) void add_kernel(
    const float* __restrict__ h, const float* __restrict__ r, float* __restrict__ h_in)
{
    const int i = (blockIdx.x * 256 + threadIdx.x) * 4;
    float4 a = *reinterpret_cast<const float4*>(&h[i]);
    float4 b = *reinterpret_cast<const float4*>(&r[i]);
    a.x += b.x; a.y += b.y; a.z += b.z; a.w += b.w;
    *reinterpret_cast<float4*>(&h_in[i]) = a;
}

extern "C" void kernel_launch(void* const* d_in, const int* in_sizes, int n_in,
                              void* d_out, int out_size, void* d_ws, size_t ws_size,
                              hipStream_t stream) {
    const float* x   = (const float*)d_in[0];  // targets [32,128,1024]
    const float* sup = (const float*)d_in[1];  // [32,64,5,1024]
    const float* Wih = (const float*)d_in[2];  // [4096,1024]
    const float* Whh = (const float*)d_in[3];  // [4096,1024]
    const float* bih = (const float*)d_in[4];  // [4096]
    const float* bhh = (const float*)d_in[5];  // [4096]
    float* out = (float*)d_out;

    char* ws = (char*)d_ws;
    float* Gx  = (float*)ws;                                  // 64 MB
    float* h   = (float*)(ws + (size_t)64 * 1024 * 1024);     // 16 MB
    float* c   = h + (size_t)M_ROWS * E_DIM;                  // 16 MB
    float* r   = c + (size_t)M_ROWS * E_DIM;                  // 16 MB
    float* hin = r + (size_t)M_ROWS * E_DIM;                  // 16 MB

    // zero h, c, r (contiguous)
    hipMemsetAsync(h, 0, (size_t)3 * M_ROWS * E_DIM * sizeof(float), stream);

    // Gx = x @ W_ih^T + b_ih + b_hh   (loop-invariant)
    gemm_bias_kernel<<<dim3(64, 64), 256, 0, stream>>>(x, Wih, bih, bhh, Gx);

    for (int s = 0; s < K_STEPS; ++s) {
        add_kernel<<<4096, 256, 0, stream>>>(h, r, hin);
        attn_kernel<<<M_ROWS, 256, 0, stream>>>(hin, sup, r);
        lstm_step_kernel<<<dim3(16, 64), 256, 0, stream>>>(hin, Whh, Gx, x, h, c);
    }

    hipMemcpyAsync(out, h, (size_t)M_ROWS * E_DIM * sizeof(float),
                   hipMemcpyDeviceToDevice, stream);
}

// Round 3
// 4174.275 us; speedup vs baseline: 2.0691x; 2.0691x over previous
//
#include <hip/hip_runtime.h>
#include <math.h>

#define E_DIM   1024
#define M_ROWS  4096
#define NKP     320
#define GATES_N 4096
#define MF      (M_ROWS * E_DIM)   // 4,194,304

typedef __attribute__((ext_vector_type(8))) short bf16x8;
typedef __attribute__((ext_vector_type(4))) float f32x4;

// ---- persistent device state ----
__device__ float          g_Gx[(size_t)M_ROWS * GATES_N];  // x@Wih^T + biases (loop-invariant, fp32)
__device__ float          g_h[MF];
__device__ float          g_c[MF];
__device__ float          g_r[MF];
__device__ float          g_ST[(size_t)32 * E_DIM * NKP];  // S^T per batch: [b][k][j]
__device__ unsigned short g_hinh[MF], g_hinl[MF];          // split bf16 of h+r
__device__ unsigned short g_xh[MF],   g_xl[MF];            // split bf16 of x
__device__ unsigned short g_Wihh[MF], g_Wihl[MF];
__device__ unsigned short g_Whhh[MF], g_Whhl[MF];

__device__ __forceinline__ unsigned short f2bf(float f) {
    unsigned int u = __builtin_bit_cast(unsigned int, f);
    return (unsigned short)((u + 0x7fffu + ((u >> 16) & 1u)) >> 16);  // RNE
}
__device__ __forceinline__ float bf2f(unsigned short s) {
    unsigned int u = ((unsigned int)s) << 16;
    return __builtin_bit_cast(float, u);
}
__device__ __forceinline__ void split_bf(float v, unsigned short& hi, unsigned short& lo) {
    hi = f2bf(v);
    lo = f2bf(v - bf2f(hi));
}
__device__ __forceinline__ float sigmoid_f(float v) { return 1.f / (1.f + __expf(-v)); }
__device__ __forceinline__ float tanh_f(float v) {
    const float vc = fminf(fmaxf(v, -15.f), 15.f);
    const float t = __expf(2.f * vc);
    return (t - 1.f) / (t + 1.f);
}

// ---------------------------------------------------------------------------
// prep: split-convert Wih/Whh/x to bf16 hi/lo, zero h/c/r.
// ---------------------------------------------------------------------------
__global__ __launch_bounds__(256) void prep_kernel(
    const float* __restrict__ Wih, const float* __restrict__ Whh,
    const float* __restrict__ x)
{
    const int i = blockIdx.x * 256 + threadIdx.x;  // < 1,048,576 (x4 elems)
    const float4 w4 = reinterpret_cast<const float4*>(Wih)[i];
    const float4 v4 = reinterpret_cast<const float4*>(Whh)[i];
    const float4 x4 = reinterpret_cast<const float4*>(x)[i];
    ushort4 ah, al, bh, bl, ch, cl;
    split_bf(w4.x, ah.x, al.x); split_bf(w4.y, ah.y, al.y);
    split_bf(w4.z, ah.z, al.z); split_bf(w4.w, ah.w, al.w);
    split_bf(v4.x, bh.x, bl.x); split_bf(v4.y, bh.y, bl.y);
    split_bf(v4.z, bh.z, bl.z); split_bf(v4.w, bh.w, bl.w);
    split_bf(x4.x, ch.x, cl.x); split_bf(x4.y, ch.y, cl.y);
    split_bf(x4.z, ch.z, cl.z); split_bf(x4.w, ch.w, cl.w);
    reinterpret_cast<ushort4*>(g_Wihh)[i] = ah; reinterpret_cast<ushort4*>(g_Wihl)[i] = al;
    reinterpret_cast<ushort4*>(g_Whhh)[i] = bh; reinterpret_cast<ushort4*>(g_Whhl)[i] = bl;
    reinterpret_cast<ushort4*>(g_xh)[i]   = ch; reinterpret_cast<ushort4*>(g_xl)[i]   = cl;
    const float4 z = make_float4(0.f, 0.f, 0.f, 0.f);
    reinterpret_cast<float4*>(g_h)[i] = z;
    reinterpret_cast<float4*>(g_c)[i] = z;
    reinterpret_cast<float4*>(g_r)[i] = z;
}

// ---------------------------------------------------------------------------
// transpose S: [32][320][1024] -> g_ST [32][1024][320]
// ---------------------------------------------------------------------------
__global__ __launch_bounds__(256) void transpose_S_kernel(const float* __restrict__ S)
{
    __shared__ float t[64][65];
    const int b = blockIdx.z, j0 = blockIdx.y * 64, k0 = blockIdx.x * 64;
    const float* Sb = S + (size_t)b * NKP * E_DIM;
    float* STb = g_ST + (size_t)b * E_DIM * NKP;
    const int c = threadIdx.x & 63, r4 = threadIdx.x >> 6;
    #pragma unroll
    for (int i = 0; i < 16; ++i) {
        const int row = r4 * 16 + i;
        t[row][c] = Sb[(size_t)(j0 + row) * E_DIM + k0 + c];
    }
    __syncthreads();
    #pragma unroll
    for (int i = 0; i < 16; ++i) {
        const int row = r4 * 16 + i;
        STb[(size_t)(k0 + row) * NKP + j0 + c] = t[c][row];
    }
}

// ---------------------------------------------------------------------------
// Split-bf16 fused MFMA GEMM (3-term: Ah*Bh + Al*Bh + Ah*Bl).
// C = A[4096x1024] @ B^T, B gate-interleaved (BN = 32 e-cols x 4 gates).
//   MODE 0: A=x, B=Wih  -> g_Gx + b_ih + b_hh
//   MODE 1: A=h_in, B=Whh -> full LSTM cell epilogue (writes g_c, g_h, d_out)
// Block: 128 rows x 128 cols, 4 waves, wave = 32 rows x 128 cols.
// ---------------------------------------------------------------------------
template<int MODE>
__global__ __launch_bounds__(256) void gemm_fused(
    const float* __restrict__ p0, const float* __restrict__ p1,
    float* __restrict__ outp, const int do_out)
{
    __shared__ __align__(16) unsigned short Ah[128 * 32];
    __shared__ __align__(16) unsigned short Al[128 * 32];
    __shared__ __align__(16) unsigned short Bh[128 * 32];
    __shared__ __align__(16) unsigned short Bl[128 * 32];
    const unsigned short* __restrict__ Abh = (MODE == 0) ? g_xh   : g_hinh;
    const unsigned short* __restrict__ Abl = (MODE == 0) ? g_xl   : g_hinl;
    const unsigned short* __restrict__ Bbh = (MODE == 0) ? g_Wihh : g_Whhh;
    const unsigned short* __restrict__ Bbl = (MODE == 0) ? g_Wihl : g_Whhl;
    const int tid = threadIdx.x, l = tid & 63, w = tid >> 6;
    int bid = blockIdx.x;
    bid = (bid & 7) * 128 + (bid >> 3);            // XCD swizzle (1024 = 8*128)
    const int row0 = (bid >> 5) * 128, e0 = (bid & 31) * 32;
    const int b15 = l & 15, koff = (l >> 4) * 8;
    const int arow = w * 32 + b15;
    f32x4 acc[2][8] = {};

    for (int kt = 0; kt < E_DIM; kt += 32) {
        #pragma unroll
        for (int half = 0; half < 2; ++half) {
            const int slot = half * 256 + tid;      // 0..511
            const int rt = slot >> 2, kb = (slot & 3) * 8;
            const int ldsoff = (half * 256 + w * 64) * 16;  // wave-uniform byte base
            const size_t aidx = (size_t)(row0 + rt) * E_DIM + kt + kb;
            const int gt = rt >> 5, er = rt & 31;
            const size_t bidx = (size_t)(gt * E_DIM + e0 + er) * E_DIM + kt + kb;
            __builtin_amdgcn_global_load_lds(
                (const __attribute__((address_space(1))) void*)&Abh[aidx],
                (__attribute__((address_space(3))) void*)((char*)Ah + ldsoff), 16, 0, 0);
            __builtin_amdgcn_global_load_lds(
                (const __attribute__((address_space(1))) void*)&Abl[aidx],
                (__attribute__((address_space(3))) void*)((char*)Al + ldsoff), 16, 0, 0);
            __builtin_amdgcn_global_load_lds(
                (const __attribute__((address_space(1))) void*)&Bbh[bidx],
                (__attribute__((address_space(3))) void*)((char*)Bh + ldsoff), 16, 0, 0);
            __builtin_amdgcn_global_load_lds(
                (const __attribute__((address_space(1))) void*)&Bbl[bidx],
                (__attribute__((address_space(3))) void*)((char*)Bl + ldsoff), 16, 0, 0);
        }
        __syncthreads();
        bf16x8 avh[2], avl[2];
        #pragma unroll
        for (int m = 0; m < 2; ++m) {
            avh[m] = *reinterpret_cast<const bf16x8*>(&Ah[(arow + m * 16) * 32 + koff]);
            avl[m] = *reinterpret_cast<const bf16x8*>(&Al[(arow + m * 16) * 32 + koff]);
        }
        #pragma unroll
        for (int n = 0; n < 8; ++n) {
            const bf16x8 bvh = *reinterpret_cast<const bf16x8*>(&Bh[(n * 16 + b15) * 32 + koff]);
            const bf16x8 bvl = *reinterpret_cast<const bf16x8*>(&Bl[(n * 16 + b15) * 32 + koff]);
            #pragma unroll
            for (int m = 0; m < 2; ++m) {
                acc[m][n] = __builtin_amdgcn_mfma_f32_16x16x32_bf16(avh[m], bvl, acc[m][n], 0, 0, 0);
                acc[m][n] = __builtin_amdgcn_mfma_f32_16x16x32_bf16(avl[m], bvh, acc[m][n], 0, 0, 0);
                acc[m][n] = __builtin_amdgcn_mfma_f32_16x16x32_bf16(avh[m], bvh, acc[m][n], 0, 0, 0);
            }
        }
        __syncthreads();
    }

    const int rbase = row0 + w * 32 + (l >> 4) * 4;
    if (MODE == 0) {
        #pragma unroll
        for (int m = 0; m < 2; ++m)
            #pragma unroll
            for (int n = 0; n < 8; ++n) {
                const int col = n * 16 + b15;                        // 0..127
                const int gcol = (col >> 5) * E_DIM + e0 + (col & 31);
                const float add = p0[gcol] + p1[gcol];
                #pragma unroll
                for (int q = 0; q < 4; ++q) {
                    const int row = rbase + m * 16 + q;
                    g_Gx[(size_t)row * GATES_N + gcol] = acc[m][n][q] + add;
                }
            }
    } else {
        #pragma unroll
        for (int m = 0; m < 2; ++m)
            #pragma unroll
            for (int er16 = 0; er16 < 2; ++er16) {
                const int e = e0 + er16 * 16 + b15;
                #pragma unroll
                for (int q = 0; q < 4; ++q) {
                    const int row = rbase + m * 16 + q;
                    const size_t gb = (size_t)row * GATES_N + e;
                    const float gi = acc[m][0 + er16][q] + g_Gx[gb];
                    const float gf = acc[m][2 + er16][q] + g_Gx[gb + E_DIM];
                    const float gg = acc[m][4 + er16][q] + g_Gx[gb + 2 * E_DIM];
                    const float go = acc[m][6 + er16][q] + g_Gx[gb + 3 * E_DIM];
                    const size_t he = (size_t)row * E_DIM + e;
                    const float cn = sigmoid_f(gf) * g_c[he] + sigmoid_f(gi) * tanh_f(gg);
                    g_c[he] = cn;
                    const float hn = sigmoid_f(go) * tanh_f(cn) + p0[he];  // p0 = x
                    g_h[he] = hn;
                    if (do_out) outp[he] = hn;
                }
            }
    }
}

// ---------------------------------------------------------------------------
// split bf16 of h_in = h + r
// ---------------------------------------------------------------------------
__global__ __launch_bounds__(256) void add_split_kernel()
{
    const int i = blockIdx.x * 256 + threadIdx.x;
    const float4 a = reinterpret_cast<const float4*>(g_h)[i];
    const float4 b = reinterpret_cast<const float4*>(g_r)[i];
    ushort4 oh, ol;
    split_bf(a.x + b.x, oh.x, ol.x);
    split_bf(a.y + b.y, oh.y, ol.y);
    split_bf(a.z + b.z, oh.z, ol.z);
    split_bf(a.w + b.w, oh.w, ol.w);
    reinterpret_cast<ushort4*>(g_hinh)[i] = oh;
    reinterpret_cast<ushort4*>(g_hinl)[i] = ol;
}

// ---------------------------------------------------------------------------
// attention (fp32). Block = 16 (b,t) rows; grid 256 = 32 b x 8 chunks.
// ---------------------------------------------------------------------------
__global__ __launch_bounds__(256) void attn_kernel(const float* __restrict__ sup)
{
    __shared__ __align__(16) float attT[NKP][20];   // [j][row], padded
    const int b = blockIdx.x >> 3, chunk = blockIdx.x & 7;
    const int bt0 = b * 128 + chunk * 16;
    const int tid = threadIdx.x, w = tid >> 6, l = tid & 63;

    // phase 1: warp w -> rows 4w..4w+3; lane l owns j = l + 64*jj
    {
        float p[4][5] = {};
        const float* STb = g_ST + (size_t)b * E_DIM * NKP;
        for (int k4 = 0; k4 < E_DIM; k4 += 4) {
            float qa[4][4];
            #pragma unroll
            for (int rr = 0; rr < 4; ++rr) {
                const size_t qi = (size_t)(bt0 + w * 4 + rr) * E_DIM + k4;
                const float4 hh = *reinterpret_cast<const float4*>(&g_h[qi]);
                const float4 rv = *reinterpret_cast<const float4*>(&g_r[qi]);
                qa[rr][0] = hh.x + rv.x; qa[rr][1] = hh.y + rv.y;
                qa[rr][2] = hh.z + rv.z; qa[rr][3] = hh.w + rv.w;
            }
            #pragma unroll
            for (int kk = 0; kk < 4; ++kk) {
                const float* Sk = STb + (size_t)(k4 + kk) * NKP + l;
                const float sv0 = Sk[0], sv1 = Sk[64], sv2 = Sk[128],
                            sv3 = Sk[192], sv4 = Sk[256];
                #pragma unroll
                for (int rr = 0; rr < 4; ++rr) {
                    const float q = qa[rr][kk];
                    p[rr][0] += q * sv0; p[rr][1] += q * sv1; p[rr][2] += q * sv2;
                    p[rr][3] += q * sv3; p[rr][4] += q * sv4;
                }
            }
        }
        #pragma unroll
        for (int rr = 0; rr < 4; ++rr)
            #pragma unroll
            for (int jj = 0; jj < 5; ++jj)
                attT[l + 64 * jj][w * 4 + rr] = p[rr][jj];
    }
    __syncthreads();

    // phase 2: softmax per row over 320
    #pragma unroll
    for (int rr = 0; rr < 4; ++rr) {
        const int row = w * 4 + rr;
        float v[5];
        #pragma unroll
        for (int jj = 0; jj < 5; ++jj) v[jj] = attT[l + 64 * jj][row];
        float mx = fmaxf(fmaxf(fmaxf(v[0], v[1]), fmaxf(v[2], v[3])), v[4]);
        #pragma unroll
        for (int off = 32; off; off >>= 1) mx = fmaxf(mx, __shfl_xor(mx, off));
        float e[5], s = 0.f;
        #pragma unroll
        for (int jj = 0; jj < 5; ++jj) { e[jj] = __expf(v[jj] - mx); s += e[jj]; }
        #pragma unroll
        for (int off = 32; off; off >>= 1) s += __shfl_xor(s, off);
        const float inv = 1.f / s;
        #pragma unroll
        for (int jj = 0; jj < 5; ++jj) attT[l + 64 * jj][row] = e[jj] * inv;
    }
    __syncthreads();

    // phase 3: r = att @ S. Warp w owns cols [w*256,+256), lane l -> 4 cols.
    {
        const float* Sb = sup + (size_t)b * NKP * E_DIM;
        const int ecol = w * 256 + l * 4;
        float4 acc[16];
        #pragma unroll
        for (int rr = 0; rr < 16; ++rr) acc[rr] = make_float4(0.f, 0.f, 0.f, 0.f);
        for (int j = 0; j < NKP; ++j) {
            const float4 s4 = *reinterpret_cast<const float4*>(&Sb[(size_t)j * E_DIM + ecol]);
            const float4 a0 = *reinterpret_cast<const float4*>(&attT[j][0]);
            const float4 a1 = *reinterpret_cast<const float4*>(&attT[j][4]);
            const float4 a2 = *reinterpret_cast<const float4*>(&attT[j][8]);
            const float4 a3 = *reinterpret_cast<const float4*>(&attT[j][12]);
            const float wv[16] = {a0.x, a0.y, a0.z, a0.w, a1.x, a1.y, a1.z, a1.w,
                                  a2.x, a2.y, a2.z, a2.w, a3.x, a3.y, a3.z, a3.w};
            #pragma unroll
            for (int rr = 0; rr < 16; ++rr) {
                acc[rr].x += wv[rr] * s4.x; acc[rr].y += wv[rr] * s4.y;
                acc[rr].z += wv[rr] * s4.z; acc[rr].w += wv[rr] * s4.w;
            }
        }
        #pragma unroll
        for (int rr = 0; rr < 16; ++rr)
            *reinterpret_cast<float4*>(&g_r[(size_t)(bt0 + rr) * E_DIM + ecol]) = acc[rr];
    }
}

extern "C" void kernel_launch(void* const* d_in, const int* in_sizes, int n_in,
                              void* d_out, int out_size, void* d_ws, size_t ws_size,
                              hipStream_t stream) {
    const float* x   = (const float*)d_in[0];
    const float* sup = (const float*)d_in[1];
    const float* Wih = (const float*)d_in[2];
    const float* Whh = (const float*)d_in[3];
    const float* bih = (const float*)d_in[4];
    const float* bhh = (const float*)d_in[5];
    float* out = (float*)d_out;

    prep_kernel<<<4096, 256, 0, stream>>>(Wih, Whh, x);
    transpose_S_kernel<<<dim3(16, 5, 32), 256, 0, stream>>>(sup);
    gemm_fused<0><<<1024, 256, 0, stream>>>(bih, bhh, nullptr, 0);

    for (int s = 0; s < 8; ++s) {
        add_split_kernel<<<4096, 256, 0, stream>>>();
        if (s < 7) attn_kernel<<<256, 256, 0, stream>>>(sup);
        gemm_fused<1><<<1024, 256, 0, stream>>>(x, nullptr, out, s == 7 ? 1 : 0);
    }
}

// Round 4
// 3695.414 us; speedup vs baseline: 2.3372x; 1.1296x over previous
//
#include <hip/hip_runtime.h>
#include <math.h>

#define E_DIM   1024
#define M_ROWS  4096
#define NKP     320
#define GATES_N 4096
#define MF      (M_ROWS * E_DIM)          // 4,194,304
#define SF      ((size_t)32 * NKP * E_DIM) // 10,485,760
#define ATT_ST  336

typedef __attribute__((ext_vector_type(8))) short bf16x8;
typedef __attribute__((ext_vector_type(4))) float f32x4;

// ---- persistent device state ----
__device__ float          g_Gx[(size_t)M_ROWS * GATES_N];
__device__ float          g_h[MF], g_c[MF], g_r[MF];
__device__ unsigned short g_hinh[MF], g_hinm[MF], g_hinl[MF];   // 3-split of h+r
__device__ unsigned short g_xh[MF],   g_xm[MF];                 // 2-split of x
__device__ unsigned short g_Wihh[MF], g_Wihm[MF];
__device__ unsigned short g_Whhh[MF], g_Whhm[MF];
__device__ unsigned short g_Sh[SF], g_Sm[SF], g_Sl[SF];         // 3-split S [b][j][k]
__device__ unsigned short g_STh[SF], g_STm[SF];                 // 2-split S^T [b][k][j]

__device__ __forceinline__ unsigned short f2bf(float f) {
    unsigned int u = __builtin_bit_cast(unsigned int, f);
    return (unsigned short)((u + 0x7fffu + ((u >> 16) & 1u)) >> 16);  // RNE
}
__device__ __forceinline__ float bf2f(unsigned short s) {
    unsigned int u = ((unsigned int)s) << 16;
    return __builtin_bit_cast(float, u);
}
__device__ __forceinline__ void split2(float v, unsigned short& hi, unsigned short& mi) {
    hi = f2bf(v); mi = f2bf(v - bf2f(hi));
}
__device__ __forceinline__ void split3(float v, unsigned short& hi, unsigned short& mi,
                                       unsigned short& lo) {
    hi = f2bf(v);
    const float r1 = v - bf2f(hi);
    mi = f2bf(r1);
    lo = f2bf(r1 - bf2f(mi));
}
__device__ __forceinline__ float sigmoid_f(float v) { return 1.f / (1.f + __expf(-v)); }
__device__ __forceinline__ float tanh_f(float v) {
    const float vc = fminf(fmaxf(v, -15.f), 15.f);
    const float t = __expf(2.f * vc);
    return (t - 1.f) / (t + 1.f);
}

union SharedU {
    struct { unsigned short Ah[4096], Am[4096], Bh[4096], Bm[4096]; } g;  // 32 KB
    struct {
        unsigned short ah[32][ATT_ST], am[32][ATT_ST];                    // 43 KB
        float red_m[4][32], red_s[4][32];
    } a;
};

// ---------------------------------------------------------------------------
// prep: split weights (2-way) and x (2-way); zero h/c/r
// ---------------------------------------------------------------------------
__global__ __launch_bounds__(256) void prep_kernel(
    const float* __restrict__ Wih, const float* __restrict__ Whh,
    const float* __restrict__ x)
{
    const int i = blockIdx.x * 256 + threadIdx.x;   // x4 elements
    const float4 w4 = reinterpret_cast<const float4*>(Wih)[i];
    const float4 v4 = reinterpret_cast<const float4*>(Whh)[i];
    const float4 x4 = reinterpret_cast<const float4*>(x)[i];
    ushort4 ah, am, bh, bm, ch, cm;
    split2(w4.x, ah.x, am.x); split2(w4.y, ah.y, am.y);
    split2(w4.z, ah.z, am.z); split2(w4.w, ah.w, am.w);
    split2(v4.x, bh.x, bm.x); split2(v4.y, bh.y, bm.y);
    split2(v4.z, bh.z, bm.z); split2(v4.w, bh.w, bm.w);
    split2(x4.x, ch.x, cm.x); split2(x4.y, ch.y, cm.y);
    split2(x4.z, ch.z, cm.z); split2(x4.w, ch.w, cm.w);
    reinterpret_cast<ushort4*>(g_Wihh)[i] = ah; reinterpret_cast<ushort4*>(g_Wihm)[i] = am;
    reinterpret_cast<ushort4*>(g_Whhh)[i] = bh; reinterpret_cast<ushort4*>(g_Whhm)[i] = bm;
    reinterpret_cast<ushort4*>(g_xh)[i]   = ch; reinterpret_cast<ushort4*>(g_xm)[i]   = cm;
    const float4 z = make_float4(0.f, 0.f, 0.f, 0.f);
    reinterpret_cast<float4*>(g_h)[i] = z;
    reinterpret_cast<float4*>(g_c)[i] = z;
    reinterpret_cast<float4*>(g_r)[i] = z;
}

// ---------------------------------------------------------------------------
// split S (3-way, straight) + S^T (2-way, transposed). 64x64 tiles.
// ---------------------------------------------------------------------------
__global__ __launch_bounds__(256) void split_S_kernel(const float* __restrict__ S)
{
    __shared__ float t[64][65];
    const int b = blockIdx.z, j0 = blockIdx.y * 64, k0 = blockIdx.x * 64;
    const float* Sb = S + (size_t)b * NKP * E_DIM;
    const int c = threadIdx.x & 63, r4 = threadIdx.x >> 6;
    #pragma unroll
    for (int i = 0; i < 16; ++i) {
        const int row = r4 * 16 + i;
        const float v = Sb[(size_t)(j0 + row) * E_DIM + k0 + c];
        t[row][c] = v;
        unsigned short hi, mi, lo;
        split3(v, hi, mi, lo);
        const size_t si = (size_t)b * NKP * E_DIM + (size_t)(j0 + row) * E_DIM + k0 + c;
        g_Sh[si] = hi; g_Sm[si] = mi; g_Sl[si] = lo;
    }
    __syncthreads();
    #pragma unroll
    for (int i = 0; i < 16; ++i) {
        const int row = r4 * 16 + i;            // k-offset within tile
        const float v = t[c][row];              // = S[j0+c][k0+row]
        unsigned short hi, mi;
        split2(v, hi, mi);
        const size_t sti = (size_t)b * E_DIM * NKP + (size_t)(k0 + row) * NKP + j0 + c;
        g_STh[sti] = hi; g_STm[sti] = mi;
    }
}

// ---------------------------------------------------------------------------
// 3-split of h_in = h + r
// ---------------------------------------------------------------------------
__global__ __launch_bounds__(256) void add_split3_kernel()
{
    const int i = blockIdx.x * 256 + threadIdx.x;
    const float4 a = reinterpret_cast<const float4*>(g_h)[i];
    const float4 b = reinterpret_cast<const float4*>(g_r)[i];
    const float v0 = a.x + b.x, v1 = a.y + b.y, v2 = a.z + b.z, v3 = a.w + b.w;
    ushort4 oh, om, ol;
    split3(v0, oh.x, om.x, ol.x); split3(v1, oh.y, om.y, ol.y);
    split3(v2, oh.z, om.z, ol.z); split3(v3, oh.w, om.w, ol.w);
    reinterpret_cast<ushort4*>(g_hinh)[i] = oh;
    reinterpret_cast<ushort4*>(g_hinm)[i] = om;
    reinterpret_cast<ushort4*>(g_hinl)[i] = ol;
}

// ---------------------------------------------------------------------------
// Gx = x @ Wih^T + b_ih + b_hh (split-bf16 3-term MFMA; loop-invariant).
// Grid 1024, block 256. B gate-interleaved (col = gate*E + e).
// ---------------------------------------------------------------------------
__global__ __launch_bounds__(256) void gemm_gx_kernel(
    const float* __restrict__ bih, const float* __restrict__ bhh)
{
    __shared__ SharedU sh;
    const int tid = threadIdx.x, l = tid & 63, w = tid >> 6;
    int bid = blockIdx.x;
    bid = (bid & 7) * 128 + (bid >> 3);
    const int row0 = (bid >> 5) * 128, e0 = (bid & 31) * 32;
    const int b15 = l & 15, koff = (l >> 4) * 8;
    const int arow = w * 32 + b15;
    f32x4 acc[2][8] = {};

    for (int kt = 0; kt < E_DIM; kt += 32) {
        #pragma unroll
        for (int half = 0; half < 2; ++half) {
            const int slot = half * 256 + tid;
            const int rt = slot >> 2, kb = (slot & 3) * 8;
            const int ldsoff = (half * 256 + w * 64) * 16;
            const size_t aidx = (size_t)(row0 + rt) * E_DIM + kt + kb;
            const int gt = rt >> 5, er = rt & 31;
            const size_t bidx = (size_t)(gt * E_DIM + e0 + er) * E_DIM + kt + kb;
            __builtin_amdgcn_global_load_lds(
                (const __attribute__((address_space(1))) void*)&g_xh[aidx],
                (__attribute__((address_space(3))) void*)((char*)sh.g.Ah + ldsoff), 16, 0, 0);
            __builtin_amdgcn_global_load_lds(
                (const __attribute__((address_space(1))) void*)&g_xm[aidx],
                (__attribute__((address_space(3))) void*)((char*)sh.g.Am + ldsoff), 16, 0, 0);
            __builtin_amdgcn_global_load_lds(
                (const __attribute__((address_space(1))) void*)&g_Wihh[bidx],
                (__attribute__((address_space(3))) void*)((char*)sh.g.Bh + ldsoff), 16, 0, 0);
            __builtin_amdgcn_global_load_lds(
                (const __attribute__((address_space(1))) void*)&g_Wihm[bidx],
                (__attribute__((address_space(3))) void*)((char*)sh.g.Bm + ldsoff), 16, 0, 0);
        }
        __syncthreads();
        bf16x8 avh[2], avm[2];
        #pragma unroll
        for (int m = 0; m < 2; ++m) {
            avh[m] = *reinterpret_cast<const bf16x8*>(&sh.g.Ah[(arow + m * 16) * 32 + koff]);
            avm[m] = *reinterpret_cast<const bf16x8*>(&sh.g.Am[(arow + m * 16) * 32 + koff]);
        }
        #pragma unroll
        for (int n = 0; n < 8; ++n) {
            const bf16x8 bvh = *reinterpret_cast<const bf16x8*>(&sh.g.Bh[(n * 16 + b15) * 32 + koff]);
            const bf16x8 bvm = *reinterpret_cast<const bf16x8*>(&sh.g.Bm[(n * 16 + b15) * 32 + koff]);
            #pragma unroll
            for (int m = 0; m < 2; ++m) {
                acc[m][n] = __builtin_amdgcn_mfma_f32_16x16x32_bf16(avh[m], bvm, acc[m][n], 0, 0, 0);
                acc[m][n] = __builtin_amdgcn_mfma_f32_16x16x32_bf16(avm[m], bvh, acc[m][n], 0, 0, 0);
                acc[m][n] = __builtin_amdgcn_mfma_f32_16x16x32_bf16(avh[m], bvh, acc[m][n], 0, 0, 0);
            }
        }
        __syncthreads();
    }

    const int rbase = row0 + w * 32 + (l >> 4) * 4;
    #pragma unroll
    for (int m = 0; m < 2; ++m)
        #pragma unroll
        for (int n = 0; n < 8; ++n) {
            const int col = n * 16 + b15;
            const int gcol = (col >> 5) * E_DIM + e0 + (col & 31);
            const float add = bih[gcol] + bhh[gcol];
            #pragma unroll
            for (int q = 0; q < 4; ++q)
                g_Gx[(size_t)(rbase + m * 16 + q) * GATES_N + gcol] = acc[m][n][q] + add;
        }
}

// ---------------------------------------------------------------------------
// Merged per-step kernel. Blocks 0..127: attention (writes g_r).
// Blocks 128..1151: h_in @ Whh^T + LSTM cell (writes g_h, g_c, out).
// Roles are independent given add_split3's output; disjoint writes.
// ---------------------------------------------------------------------------
__global__ __launch_bounds__(256, 3) void step_kernel(
    const float* __restrict__ x, float* __restrict__ outp, const int step)
{
    __shared__ SharedU sh;
    const int tid = threadIdx.x, l = tid & 63, w = tid >> 6;
    const int b15 = l & 15, lg = l >> 4, koff8 = lg * 8;

    if (blockIdx.x < 128) {
        // ================= attention role =================
        if (step == 7) return;                       // final r is dead
        const int b = blockIdx.x >> 2, chunk = blockIdx.x & 3;
        const int rowbase = b * 128 + chunk * 32;
        const size_t sbase  = (size_t)b * NKP * E_DIM;
        const size_t stbase = (size_t)b * E_DIM * NKP;

        // --- QK^T: 3-split x 3-split, 6 terms. Wave w owns cols w*80..+80 ---
        f32x4 qacc[2][5] = {};
        for (int kt = 0; kt < E_DIM; kt += 32) {
            bf16x8 qh[2], qm[2], ql[2];
            #pragma unroll
            for (int m = 0; m < 2; ++m) {
                const size_t qi = (size_t)(rowbase + m * 16 + b15) * E_DIM + kt + koff8;
                qh[m] = *reinterpret_cast<const bf16x8*>(&g_hinh[qi]);
                qm[m] = *reinterpret_cast<const bf16x8*>(&g_hinm[qi]);
                ql[m] = *reinterpret_cast<const bf16x8*>(&g_hinl[qi]);
            }
            #pragma unroll
            for (int n = 0; n < 5; ++n) {
                const size_t si = sbase + (size_t)(w * 80 + n * 16 + b15) * E_DIM + kt + koff8;
                const bf16x8 svh = *reinterpret_cast<const bf16x8*>(&g_Sh[si]);
                const bf16x8 svm = *reinterpret_cast<const bf16x8*>(&g_Sm[si]);
                const bf16x8 svl = *reinterpret_cast<const bf16x8*>(&g_Sl[si]);
                #pragma unroll
                for (int m = 0; m < 2; ++m) {
                    f32x4 a = qacc[m][n];
                    a = __builtin_amdgcn_mfma_f32_16x16x32_bf16(qh[m], svl, a, 0, 0, 0);
                    a = __builtin_amdgcn_mfma_f32_16x16x32_bf16(ql[m], svh, a, 0, 0, 0);
                    a = __builtin_amdgcn_mfma_f32_16x16x32_bf16(qm[m], svm, a, 0, 0, 0);
                    a = __builtin_amdgcn_mfma_f32_16x16x32_bf16(qh[m], svm, a, 0, 0, 0);
                    a = __builtin_amdgcn_mfma_f32_16x16x32_bf16(qm[m], svh, a, 0, 0, 0);
                    a = __builtin_amdgcn_mfma_f32_16x16x32_bf16(qh[m], svh, a, 0, 0, 0);
                    qacc[m][n] = a;
                }
            }
        }

        // --- softmax over 320 (fp32, cross-wave via LDS) ---
        float vmax[2][4];
        #pragma unroll
        for (int m = 0; m < 2; ++m)
            #pragma unroll
            for (int q = 0; q < 4; ++q) {
                float mx = qacc[m][0][q];
                #pragma unroll
                for (int n = 1; n < 5; ++n) mx = fmaxf(mx, qacc[m][n][q]);
                #pragma unroll
                for (int mk = 1; mk < 16; mk <<= 1) mx = fmaxf(mx, __shfl_xor(mx, mk));
                vmax[m][q] = mx;
                if (b15 == 0) sh.a.red_m[w][m * 16 + lg * 4 + q] = mx;
            }
        __syncthreads();
        float inv[2][4];
        #pragma unroll
        for (int m = 0; m < 2; ++m)
            #pragma unroll
            for (int q = 0; q < 4; ++q) {
                const int row = m * 16 + lg * 4 + q;
                const float mx = fmaxf(fmaxf(sh.a.red_m[0][row], sh.a.red_m[1][row]),
                                       fmaxf(sh.a.red_m[2][row], sh.a.red_m[3][row]));
                vmax[m][q] = mx;
                float s = 0.f;
                #pragma unroll
                for (int n = 0; n < 5; ++n) {
                    const float e = __expf(qacc[m][n][q] - mx);
                    qacc[m][n][q] = e;
                    s += e;
                }
                #pragma unroll
                for (int mk = 1; mk < 16; mk <<= 1) s += __shfl_xor(s, mk);
                if (b15 == 0) sh.a.red_s[w][row] = s;
            }
        __syncthreads();
        #pragma unroll
        for (int m = 0; m < 2; ++m)
            #pragma unroll
            for (int q = 0; q < 4; ++q) {
                const int row = m * 16 + lg * 4 + q;
                inv[m][q] = 1.f / (sh.a.red_s[0][row] + sh.a.red_s[1][row] +
                                   sh.a.red_s[2][row] + sh.a.red_s[3][row]);
            }
        // write att (2-split) to LDS in A-fragment layout
        #pragma unroll
        for (int m = 0; m < 2; ++m)
            #pragma unroll
            for (int n = 0; n < 5; ++n)
                #pragma unroll
                for (int q = 0; q < 4; ++q) {
                    const float a = qacc[m][n][q] * inv[m][q];
                    unsigned short hi, mi;
                    split2(a, hi, mi);
                    const int row = m * 16 + lg * 4 + q, col = w * 80 + n * 16 + b15;
                    sh.a.ah[row][col] = hi;
                    sh.a.am[row][col] = mi;
                }
        __syncthreads();

        // --- PV: r = att @ ST^T (2-split x 2-split, 3 terms). 4 passes/wave ---
        #pragma unroll 1
        for (int pass = 0; pass < 4; ++pass) {
            const int ebase = w * 256 + pass * 64;
            f32x4 pacc[2][4] = {};
            for (int jt = 0; jt < NKP; jt += 32) {
                bf16x8 pah[2], pam[2];
                #pragma unroll
                for (int m = 0; m < 2; ++m) {
                    pah[m] = *reinterpret_cast<const bf16x8*>(&sh.a.ah[m * 16 + b15][jt + koff8]);
                    pam[m] = *reinterpret_cast<const bf16x8*>(&sh.a.am[m * 16 + b15][jt + koff8]);
                }
                #pragma unroll
                for (int n = 0; n < 4; ++n) {
                    const size_t sti = stbase + (size_t)(ebase + n * 16 + b15) * NKP + jt + koff8;
                    const bf16x8 sth = *reinterpret_cast<const bf16x8*>(&g_STh[sti]);
                    const bf16x8 stm = *reinterpret_cast<const bf16x8*>(&g_STm[sti]);
                    #pragma unroll
                    for (int m = 0; m < 2; ++m) {
                        f32x4 a = pacc[m][n];
                        a = __builtin_amdgcn_mfma_f32_16x16x32_bf16(pah[m], stm, a, 0, 0, 0);
                        a = __builtin_amdgcn_mfma_f32_16x16x32_bf16(pam[m], sth, a, 0, 0, 0);
                        a = __builtin_amdgcn_mfma_f32_16x16x32_bf16(pah[m], sth, a, 0, 0, 0);
                        pacc[m][n] = a;
                    }
                }
            }
            #pragma unroll
            for (int m = 0; m < 2; ++m)
                #pragma unroll
                for (int n = 0; n < 4; ++n)
                    #pragma unroll
                    for (int q = 0; q < 4; ++q)
                        g_r[(size_t)(rowbase + m * 16 + lg * 4 + q) * E_DIM +
                            ebase + n * 16 + b15] = pacc[m][n][q];
        }
        return;
    }

    // ================= GEMM + LSTM role =================
    int bid = blockIdx.x - 128;
    bid = (bid & 7) * 128 + (bid >> 3);            // XCD swizzle
    const int row0 = (bid >> 5) * 128, e0 = (bid & 31) * 32;
    const int koff = koff8;
    const int arow = w * 32 + b15;
    f32x4 acc[2][8] = {};

    for (int kt = 0; kt < E_DIM; kt += 32) {
        #pragma unroll
        for (int half = 0; half < 2; ++half) {
            const int slot = half * 256 + tid;
            const int rt = slot >> 2, kb = (slot & 3) * 8;
            const int ldsoff = (half * 256 + w * 64) * 16;
            const size_t aidx = (size_t)(row0 + rt) * E_DIM + kt + kb;
            const int gt = rt >> 5, er = rt & 31;
            const size_t bidx = (size_t)(gt * E_DIM + e0 + er) * E_DIM + kt + kb;
            __builtin_amdgcn_global_load_lds(
                (const __attribute__((address_space(1))) void*)&g_hinh[aidx],
                (__attribute__((address_space(3))) void*)((char*)sh.g.Ah + ldsoff), 16, 0, 0);
            __builtin_amdgcn_global_load_lds(
                (const __attribute__((address_space(1))) void*)&g_hinm[aidx],
                (__attribute__((address_space(3))) void*)((char*)sh.g.Am + ldsoff), 16, 0, 0);
            __builtin_amdgcn_global_load_lds(
                (const __attribute__((address_space(1))) void*)&g_Whhh[bidx],
                (__attribute__((address_space(3))) void*)((char*)sh.g.Bh + ldsoff), 16, 0, 0);
            __builtin_amdgcn_global_load_lds(
                (const __attribute__((address_space(1))) void*)&g_Whhm[bidx],
                (__attribute__((address_space(3))) void*)((char*)sh.g.Bm + ldsoff), 16, 0, 0);
        }
        __syncthreads();
        bf16x8 avh[2], avm[2];
        #pragma unroll
        for (int m = 0; m < 2; ++m) {
            avh[m] = *reinterpret_cast<const bf16x8*>(&sh.g.Ah[(arow + m * 16) * 32 + koff]);
            avm[m] = *reinterpret_cast<const bf16x8*>(&sh.g.Am[(arow + m * 16) * 32 + koff]);
        }
        #pragma unroll
        for (int n = 0; n < 8; ++n) {
            const bf16x8 bvh = *reinterpret_cast<const bf16x8*>(&sh.g.Bh[(n * 16 + b15) * 32 + koff]);
            const bf16x8 bvm = *reinterpret_cast<const bf16x8*>(&sh.g.Bm[(n * 16 + b15) * 32 + koff]);
            #pragma unroll
            for (int m = 0; m < 2; ++m) {
                acc[m][n] = __builtin_amdgcn_mfma_f32_16x16x32_bf16(avh[m], bvm, acc[m][n], 0, 0, 0);
                acc[m][n] = __builtin_amdgcn_mfma_f32_16x16x32_bf16(avm[m], bvh, acc[m][n], 0, 0, 0);
                acc[m][n] = __builtin_amdgcn_mfma_f32_16x16x32_bf16(avh[m], bvh, acc[m][n], 0, 0, 0);
            }
        }
        __syncthreads();
    }

    const int rbase = row0 + w * 32 + lg * 4;
    const int do_out = (step == 7);
    #pragma unroll
    for (int m = 0; m < 2; ++m)
        #pragma unroll
        for (int er16 = 0; er16 < 2; ++er16) {
            const int e = e0 + er16 * 16 + b15;
            #pragma unroll
            for (int q = 0; q < 4; ++q) {
                const int row = rbase + m * 16 + q;
                const size_t gb = (size_t)row * GATES_N + e;
                const float gi = acc[m][0 + er16][q] + g_Gx[gb];
                const float gf = acc[m][2 + er16][q] + g_Gx[gb + E_DIM];
                const float gg = acc[m][4 + er16][q] + g_Gx[gb + 2 * E_DIM];
                const float go = acc[m][6 + er16][q] + g_Gx[gb + 3 * E_DIM];
                const size_t he = (size_t)row * E_DIM + e;
                const float cn = sigmoid_f(gf) * g_c[he] + sigmoid_f(gi) * tanh_f(gg);
                g_c[he] = cn;
                const float hn = sigmoid_f(go) * tanh_f(cn) + x[he];
                g_h[he] = hn;
                if (do_out) outp[he] = hn;
            }
        }
}

extern "C" void kernel_launch(void* const* d_in, const int* in_sizes, int n_in,
                              void* d_out, int out_size, void* d_ws, size_t ws_size,
                              hipStream_t stream) {
    const float* x   = (const float*)d_in[0];
    const float* sup = (const float*)d_in[1];
    const float* Wih = (const float*)d_in[2];
    const float* Whh = (const float*)d_in[3];
    const float* bih = (const float*)d_in[4];
    const float* bhh = (const float*)d_in[5];
    float* out = (float*)d_out;

    prep_kernel<<<4096, 256, 0, stream>>>(Wih, Whh, x);
    split_S_kernel<<<dim3(16, 5, 32), 256, 0, stream>>>(sup);
    gemm_gx_kernel<<<1024, 256, 0, stream>>>(bih, bhh);

    for (int s = 0; s < 8; ++s) {
        add_split3_kernel<<<4096, 256, 0, stream>>>();
        step_kernel<<<1152, 256, 0, stream>>>(x, out, s);
    }
}